// Round 1
// baseline (898.662 us; speedup 1.0000x reference)
//
#include <hip/hip_runtime.h>
#include <stdint.h>

#define CIN  128
#define COUT 256
#define HH   256
#define WW   256
#define BSZ  32
#define HB   8
#define WB   8
#define NBLK 256
#define P2   34          // padded block dim (32 + halo)
#define PIX2 1156        // 34*34
#define PITCH 40         // LDS pitch (bf16 elems) for 32-ci chunk tiles -> 80B, low bank conflict

typedef __attribute__((ext_vector_type(8))) short bfx8;
typedef __attribute__((ext_vector_type(4))) float f32x4;

#define MFMA(a,b,c) __builtin_amdgcn_mfma_f32_16x16x32_bf16((a),(b),(c),0,0,0)

static __device__ __forceinline__ float bf2f(unsigned short u){
  union { unsigned int i; float f; } v; v.i = ((unsigned int)u)<<16; return v.f;
}
static __device__ __forceinline__ unsigned short f2bf(float f){
  union { float f; unsigned int i; } v; v.f = f;
  unsigned int r = v.i + 0x7fffu + ((v.i>>16)&1u);
  return (unsigned short)(r>>16);
}

// ---------------- prep: weights -> bf16 (w2 transposed to [tap][co][ci]) ----------------
__global__ void k_prep(const float* __restrict__ w1, const float* __restrict__ wd,
                       const float* __restrict__ w2,
                       unsigned short* __restrict__ w1b, unsigned short* __restrict__ wdb,
                       unsigned short* __restrict__ w2t){
  int i = blockIdx.x*256 + threadIdx.x;
  if (i < COUT*CIN){ w1b[i] = f2bf(w1[i]); wdb[i] = f2bf(wd[i]); }
  if (i < COUT*COUT*9){
    int co = i/2304, r = i - co*2304;
    int ci = r/9,   tp = r - ci*9;
    w2t[((size_t)tp*COUT + co)*COUT + ci] = f2bf(w2[i]);
  }
}

// ---------------- active flags + inactive block list ----------------
__global__ void k_lists(const int* __restrict__ bidx, int nact,
                        int* __restrict__ flags, int* __restrict__ inact){
  int t = threadIdx.x;
  if (t < nact){
    int f = bidx[t*3]*(HB*WB) + bidx[t*3+1]*WB + bidx[t*3+2];
    flags[f] = 1;
  }
  __syncthreads();
  if (t == 0){
    int c = 0;
    for (int f = 0; f < NBLK; ++f) if (!flags[f]) inact[c++] = f;
  }
}

// ---------------- x [b][ci][h][w] f32 -> xT [b][h][w][ci] bf16 ----------------
#define XT_PITCH 136
__global__ void k_xt(const float* __restrict__ x, unsigned short* __restrict__ xT){
  __shared__ unsigned short tile[32*XT_PITCH];
  int wc = blockIdx.x, h = blockIdx.y, bi = blockIdx.z;
  int w0 = wc*32;
  int t = threadIdx.x;
  const float* xb = x + (size_t)bi*CIN*HH*WW + (size_t)h*WW + w0;
  #pragma unroll
  for (int it = 0; it < 2; ++it){
    int task = it*256 + t;
    int cp = task>>3, wq = task&7;
    int ci0 = cp*2, wl = wq*4;
    const float* p0 = xb + (size_t)ci0*(HH*WW) + wl;
    float4 a = *(const float4*)p0;
    float4 b = *(const float4*)(p0 + HH*WW);
    *(ushort2*)&tile[(wl+0)*XT_PITCH + ci0] = make_ushort2(f2bf(a.x), f2bf(b.x));
    *(ushort2*)&tile[(wl+1)*XT_PITCH + ci0] = make_ushort2(f2bf(a.y), f2bf(b.y));
    *(ushort2*)&tile[(wl+2)*XT_PITCH + ci0] = make_ushort2(f2bf(a.z), f2bf(b.z));
    *(ushort2*)&tile[(wl+3)*XT_PITCH + ci0] = make_ushort2(f2bf(a.w), f2bf(b.w));
  }
  __syncthreads();
  int w = t>>3, cg = (t&7)*16;
  unsigned short* dst = xT + (((size_t)bi*HH + h)*WW + (w0+w))*CIN + cg;
  *(bfx8*)dst     = *(bfx8*)&tile[w*XT_PITCH + cg];
  *(bfx8*)(dst+8) = *(bfx8*)&tile[w*XT_PITCH + cg + 8];
}

// ---------------- 1x1 GEMM: MODE 0 = conv1 (active -> h1p bf16), MODE 1 = base (inactive -> out f32 + bd)
template<int MODE>
__global__ __launch_bounds__(256) void k_gemm1(
    const unsigned short* __restrict__ xT, const unsigned short* __restrict__ wgt,
    const int* __restrict__ bidx, const int* __restrict__ inact,
    const float* __restrict__ bd, unsigned short* __restrict__ h1p,
    float* __restrict__ out){
  __shared__ unsigned short lds[128*PITCH];
  int rg = blockIdx.x, cot = blockIdx.y, z = blockIdx.z;
  int bi, by, bx;
  if (MODE == 0){ bi = bidx[z*3]; by = bidx[z*3+1]; bx = bidx[z*3+2]; }
  else { int fl = inact[z]; bi = fl>>6; by = (fl>>3)&7; bx = fl&7; }
  int t = threadIdx.x, l = t&63, wid = t>>6;
  int wc = wid>>1, wp = wid&1;
  int y0 = rg*4;
  int co_w = cot*128 + wc*64;
  f32x4 acc[4][4] = {};
  const unsigned short* wb = wgt + (size_t)(co_w + (l&15))*CIN + ((l>>4)*8);
  for (int kc = 0; kc < 4; ++kc){
    #pragma unroll
    for (int it = 0; it < 2; ++it){
      int i = it*256 + t;
      int pix = i>>2, g = i&3;
      int ly = pix>>5, lx = pix&31;
      const unsigned short* src = xT + (((size_t)bi*HH + (by*BSZ + y0 + ly))*WW + (bx*BSZ + lx))*CIN + kc*32 + g*8;
      *(bfx8*)&lds[pix*PITCH + g*8] = *(const bfx8*)src;
    }
    __syncthreads();
    bfx8 a0 = *(const bfx8*)(wb + kc*32);
    bfx8 a1 = *(const bfx8*)(wb + kc*32 + 16*CIN);
    bfx8 a2 = *(const bfx8*)(wb + kc*32 + 32*CIN);
    bfx8 a3 = *(const bfx8*)(wb + kc*32 + 48*CIN);
    #pragma unroll
    for (int f = 0; f < 4; ++f){
      bfx8 b = *(const bfx8*)&lds[(wp*64 + f*16 + (l&15))*PITCH + (l>>4)*8];
      acc[0][f] = MFMA(a0, b, acc[0][f]);
      acc[1][f] = MFMA(a1, b, acc[1][f]);
      acc[2][f] = MFMA(a2, b, acc[2][f]);
      acc[3][f] = MFMA(a3, b, acc[3][f]);
    }
    __syncthreads();
  }
  #pragma unroll
  for (int m = 0; m < 4; ++m){
    int co = co_w + m*16 + ((l>>4)<<2);
    #pragma unroll
    for (int f = 0; f < 4; ++f){
      int px = wp*64 + f*16 + (l&15);
      int ly = px>>5, lx = px&31;
      if (MODE == 0){
        *(ushort4*)&h1p[((size_t)z*PIX2 + (size_t)(y0+ly+1)*P2 + (lx+1))*COUT + co] =
          make_ushort4(f2bf(acc[m][f][0]), f2bf(acc[m][f][1]),
                       f2bf(acc[m][f][2]), f2bf(acc[m][f][3]));
      } else {
        int gy = by*BSZ + y0 + ly, gx = bx*BSZ + lx;
        #pragma unroll
        for (int j = 0; j < 4; ++j)
          out[(((size_t)bi*COUT + co + j)*HH + gy)*WW + gx] = acc[m][f][j] + bd[co+j];
      }
    }
  }
}

// ---------------- BN1 stats: per-channel partial sums over h1 (channel-last) ----------------
__global__ void k_stats1(const unsigned short* __restrict__ h1p, float* __restrict__ part1){
  int sp = blockIdx.x, n = blockIdx.y, t = threadIdx.x;  // t = channel
  const unsigned short* base = h1p + (size_t)n*PIX2*COUT;
  float s = 0.f, q = 0.f;
  #pragma unroll 4
  for (int i = 0; i < 128; ++i){
    int p = sp*128 + i;
    int ly = p>>5, lx = p&31;
    float v = bf2f(base[((size_t)(ly+1)*P2 + (lx+1))*COUT + t]);
    s += v; q += v*v;
  }
  float* dst = part1 + ((size_t)n*8 + sp)*512;
  dst[t] = s; dst[256+t] = q;
}

__global__ void k_fin1(const float* __restrict__ part1, const float* __restrict__ g,
                       const float* __restrict__ be, float* __restrict__ st, int nact){
  int t = threadIdx.x;
  float s = 0.f, q = 0.f;
  for (int gi = 0; gi < nact*8; ++gi){ s += part1[(size_t)gi*512 + t]; q += part1[(size_t)gi*512 + 256 + t]; }
  float inv = 1.0f/((float)nact*1024.0f);
  float mu = s*inv, var = q*inv - mu*mu;
  float sc = g[t]*rsqrtf(var + 1e-5f);
  st[t] = sc; st[256+t] = be[t] - mu*sc;
}

// ---------------- BN1 apply + ReLU in place on h1p; zero the halo ----------------
__global__ void k_bn1(unsigned short* __restrict__ h1p, const float* __restrict__ st, int total){
  int t = threadIdx.x;
  int ci0 = (t&31)*8;
  float sc[8], tc[8];
  #pragma unroll
  for (int j = 0; j < 8; ++j){ sc[j] = st[ci0+j]; tc[j] = st[256+ci0+j]; }
  #pragma unroll
  for (int it = 0; it < 4; ++it){
    int gpix = blockIdx.x*32 + it*8 + (t>>5);
    if (gpix >= total) continue;
    int n = gpix/PIX2; int p = gpix - n*PIX2;
    int row = p/P2, col = p - row*P2;
    unsigned short* addr = h1p + (size_t)gpix*COUT + ci0;
    if (row >= 1 && row <= 32 && col >= 1 && col <= 32){
      bfx8 v = *(bfx8*)addr;
      unsigned short o[8];
      #pragma unroll
      for (int j = 0; j < 8; ++j){
        float f = bf2f(((unsigned short*)&v)[j]);
        o[j] = f2bf(fmaxf(f*sc[j] + tc[j], 0.f));
      }
      *(bfx8*)addr = *(bfx8*)o;
    } else {
      bfx8 z = {};
      *(bfx8*)addr = z;
    }
  }
}

// ---------------- conv2: 3x3 as 9 accumulated GEMMs, h2 raw f32 -> d_out active positions ----------------
__global__ __launch_bounds__(256) void k_conv2(
    const unsigned short* __restrict__ h1p, const unsigned short* __restrict__ w2t,
    const int* __restrict__ bidx, float* __restrict__ out){
  __shared__ unsigned short lds[204*PITCH];
  int rg = blockIdx.x, cot = blockIdx.y, n = blockIdx.z;
  int bi = bidx[n*3], by = bidx[n*3+1], bx = bidx[n*3+2];
  int t = threadIdx.x, l = t&63, wid = t>>6;
  int wc = wid>>1, wp = wid&1;
  int y0 = rg*4;
  int co_w = cot*128 + wc*64;
  const unsigned short* tsrc = h1p + ((size_t)n*PIX2 + (size_t)y0*P2)*COUT;  // 204 contiguous padded pixels
  const unsigned short* wbase = w2t + (size_t)(co_w + (l&15))*COUT + ((l>>4)*8);
  f32x4 acc[4][4] = {};
  for (int kc = 0; kc < 8; ++kc){
    #pragma unroll
    for (int it = 0; it < 4; ++it){
      int i = it*256 + t;
      if (i < 816){
        int pix = i>>2, g = i&3;
        *(bfx8*)&lds[pix*PITCH + g*8] = *(const bfx8*)(tsrc + (size_t)pix*COUT + kc*32 + g*8);
      }
    }
    __syncthreads();
    #pragma unroll
    for (int dy = 0; dy < 3; ++dy){
      #pragma unroll
      for (int dx = 0; dx < 3; ++dx){
        const unsigned short* wt = wbase + (size_t)(dy*3+dx)*COUT*COUT + kc*32;
        bfx8 a0 = *(const bfx8*)(wt);
        bfx8 a1 = *(const bfx8*)(wt + 16*COUT);
        bfx8 a2 = *(const bfx8*)(wt + 32*COUT);
        bfx8 a3 = *(const bfx8*)(wt + 48*COUT);
        #pragma unroll
        for (int f = 0; f < 4; ++f){
          int r = wp*2 + (f>>1);
          int lx = (f&1)*16 + (l&15);
          int pix = (r+dy)*P2 + (lx+dx);
          bfx8 b = *(const bfx8*)&lds[pix*PITCH + (l>>4)*8];
          acc[0][f] = MFMA(a0, b, acc[0][f]);
          acc[1][f] = MFMA(a1, b, acc[1][f]);
          acc[2][f] = MFMA(a2, b, acc[2][f]);
          acc[3][f] = MFMA(a3, b, acc[3][f]);
        }
      }
    }
    __syncthreads();
  }
  #pragma unroll
  for (int m = 0; m < 4; ++m){
    int co = co_w + m*16 + ((l>>4)<<2);
    #pragma unroll
    for (int f = 0; f < 4; ++f){
      int r = wp*2 + (f>>1);
      int lx = (f&1)*16 + (l&15);
      int gy = by*BSZ + y0 + r, gx = bx*BSZ + lx;
      #pragma unroll
      for (int j = 0; j < 4; ++j)
        out[(((size_t)bi*COUT + co + j)*HH + gy)*WW + gx] = acc[m][f][j];
    }
  }
}

// ---------------- BN2 stats over h2 (raw, in d_out active positions) ----------------
__global__ void k_stats2(const float* __restrict__ out, const int* __restrict__ bidx,
                         float* __restrict__ part2, int nact){
  int grp = blockIdx.x, co = blockIdx.y, t = threadIdx.x;
  int bpg = nact>>3;
  int iters = (bpg<<10)>>8;
  float s = 0.f, q = 0.f;
  for (int i = 0; i < iters; ++i){
    int flat = i*256 + t;
    int n = grp*bpg + (flat>>10), p = flat&1023;
    int bi = bidx[n*3], by = bidx[n*3+1], bx = bidx[n*3+2];
    float v = out[(((size_t)bi*COUT + co)*HH + by*BSZ + (p>>5))*WW + bx*BSZ + (p&31)];
    s += v; q += v*v;
  }
  #pragma unroll
  for (int o = 32; o; o >>= 1){ s += __shfl_down(s, o, 64); q += __shfl_down(q, o, 64); }
  __shared__ float red[8];
  if ((t&63) == 0){ red[(t>>6)*2] = s; red[(t>>6)*2+1] = q; }
  __syncthreads();
  if (t == 0){
    part2[(co*8+grp)*2]   = red[0]+red[2]+red[4]+red[6];
    part2[(co*8+grp)*2+1] = red[1]+red[3]+red[5]+red[7];
  }
}

__global__ void k_fin2(const float* __restrict__ part2, const float* __restrict__ g,
                       const float* __restrict__ be, float* __restrict__ st, int nact){
  int t = threadIdx.x;
  float s = 0.f, q = 0.f;
  for (int gi = 0; gi < 8; ++gi){ s += part2[(t*8+gi)*2]; q += part2[(t*8+gi)*2+1]; }
  float inv = 1.0f/((float)nact*1024.0f);
  float mu = s*inv, var = q*inv - mu*mu;
  float sc = g[t]*rsqrtf(var + 1e-5f);
  st[t] = sc; st[256+t] = be[t] - mu*sc;
}

// ---------------- BN2 apply + ReLU in place on d_out active blocks ----------------
__global__ void k_bn2(float* __restrict__ out, const int* __restrict__ bidx,
                      const float* __restrict__ st){
  int cq = blockIdx.x, n = blockIdx.y, t = threadIdx.x;
  int bi = bidx[n*3], by = bidx[n*3+1], bx = bidx[n*3+2];
  int px0 = t*4; int ly = px0>>5, lx = px0&31;
  float* base = out + (size_t)bi*COUT*HH*WW + (size_t)(by*BSZ+ly)*WW + bx*BSZ + lx;
  for (int c = 0; c < 64; ++c){
    int co = cq*64 + c;
    float sc = st[co], tc = st[256+co];
    float4* p = (float4*)(base + (size_t)co*HH*WW);
    float4 v = *p;
    v.x = fmaxf(v.x*sc+tc, 0.f); v.y = fmaxf(v.y*sc+tc, 0.f);
    v.z = fmaxf(v.z*sc+tc, 0.f); v.w = fmaxf(v.w*sc+tc, 0.f);
    *p = v;
  }
}

extern "C" void kernel_launch(void* const* d_in, const int* in_sizes, int n_in,
                              void* d_out, int out_size, void* d_ws, size_t ws_size,
                              hipStream_t stream){
  const float* x   = (const float*)d_in[0];
  const float* w1  = (const float*)d_in[1];
  const float* g1  = (const float*)d_in[3];
  const float* be1 = (const float*)d_in[4];
  const float* w2  = (const float*)d_in[5];
  const float* g2  = (const float*)d_in[7];
  const float* be2 = (const float*)d_in[8];
  const float* wd  = (const float*)d_in[9];
  const float* bd  = (const float*)d_in[10];
  const int* bidx  = (const int*)d_in[11];
  float* out = (float*)d_out;
  const int nact = in_sizes[11]/3;     // 128
  const int ninact = NBLK - nact;

  char* wsp = (char*)d_ws;
  size_t off = 0;
  auto carve = [&](size_t bytes)->char*{
    char* p = wsp + off; off += (bytes + 255) & ~(size_t)255; return p;
  };
  unsigned short* xT  = (unsigned short*)carve((size_t)4*HH*WW*CIN*2);
  unsigned short* h1p = (unsigned short*)carve((size_t)nact*PIX2*COUT*2);
  unsigned short* w1b = (unsigned short*)carve((size_t)COUT*CIN*2);
  unsigned short* wdb = (unsigned short*)carve((size_t)COUT*CIN*2);
  unsigned short* w2t = (unsigned short*)carve((size_t)9*COUT*COUT*2);
  float* s1t1  = (float*)carve(512*4);
  float* s2t2  = (float*)carve(512*4);
  float* part1 = (float*)carve((size_t)nact*8*512*4);
  float* part2 = (float*)carve((size_t)COUT*8*2*4);
  int* flags   = (int*)carve(NBLK*4);
  int* inact   = (int*)carve(NBLK*4);

  hipMemsetAsync(flags, 0, NBLK*4, stream);
  k_lists<<<1, 256, 0, stream>>>(bidx, nact, flags, inact);
  k_prep<<<2304, 256, 0, stream>>>(w1, wd, w2, w1b, wdb, w2t);
  k_xt<<<dim3(8, HH, 4), 256, 0, stream>>>(x, xT);
  k_gemm1<0><<<dim3(8, 2, nact), 256, 0, stream>>>(xT, w1b, bidx, inact, bd, h1p, out);
  k_stats1<<<dim3(8, nact), 256, 0, stream>>>(h1p, part1);
  k_fin1<<<1, 256, 0, stream>>>(part1, g1, be1, s1t1, nact);
  {
    int total = nact*PIX2;
    k_bn1<<<(total + 31)/32, 256, 0, stream>>>(h1p, s1t1, total);
  }
  k_conv2<<<dim3(8, 2, nact), 256, 0, stream>>>(h1p, w2t, bidx, out);
  k_stats2<<<dim3(8, COUT), 256, 0, stream>>>(out, bidx, part2, nact);
  k_fin2<<<1, 256, 0, stream>>>(part2, g2, be2, s2t2, nact);
  if (ninact > 0)
    k_gemm1<1><<<dim3(8, 2, ninact), 256, 0, stream>>>(xT, wdb, bidx, inact, bd, h1p, out);
  k_bn2<<<dim3(4, nact), 256, 0, stream>>>(out, bidx, s2t2);
}

// Round 2
// 757.885 us; speedup vs baseline: 1.1857x; 1.1857x over previous
//
#include <hip/hip_runtime.h>
#include <stdint.h>

#define CIN  128
#define COUT 256
#define HH   256
#define WW   256
#define BSZ  32
#define HB   8
#define WB   8
#define NBLK 256
#define P2   34          // padded block dim (32 + halo)
#define PIX2 1156        // 34*34

typedef __attribute__((ext_vector_type(8))) short bfx8;
typedef __attribute__((ext_vector_type(4))) float f32x4;

#define MFMA(a,b,c) __builtin_amdgcn_mfma_f32_16x16x32_bf16((a),(b),(c),0,0,0)

typedef const __attribute__((address_space(1))) unsigned int gu32;
typedef __attribute__((address_space(3))) unsigned int lu32;
#define GLOAD16(g, p) __builtin_amdgcn_global_load_lds((gu32*)(g), (lu32*)(p), 16, 0, 0)

static __device__ __forceinline__ float bf2f(unsigned short u){
  union { unsigned int i; float f; } v; v.i = ((unsigned int)u)<<16; return v.f;
}
static __device__ __forceinline__ unsigned short f2bf(float f){
  union { float f; unsigned int i; } v; v.f = f;
  unsigned int r = v.i + 0x7fffu + ((v.i>>16)&1u);
  return (unsigned short)(r>>16);
}

// ---------------- prep: weights -> bf16 (w2 transposed to [tap][co][ci]) ----------------
__global__ void k_prep(const float* __restrict__ w1, const float* __restrict__ wd,
                       const float* __restrict__ w2,
                       unsigned short* __restrict__ w1b, unsigned short* __restrict__ wdb,
                       unsigned short* __restrict__ w2t){
  int i = blockIdx.x*256 + threadIdx.x;
  if (i < COUT*CIN){ w1b[i] = f2bf(w1[i]); wdb[i] = f2bf(wd[i]); }
  if (i < COUT*COUT*9){
    int co = i/2304, r = i - co*2304;
    int ci = r/9,   tp = r - ci*9;
    w2t[((size_t)tp*COUT + co)*COUT + ci] = f2bf(w2[i]);
  }
}

// ---------------- active flags + inactive block list ----------------
__global__ void k_lists(const int* __restrict__ bidx, int nact,
                        int* __restrict__ flags, int* __restrict__ inact){
  int t = threadIdx.x;
  if (t < nact){
    int f = bidx[t*3]*(HB*WB) + bidx[t*3+1]*WB + bidx[t*3+2];
    flags[f] = 1;
  }
  __syncthreads();
  if (t == 0){
    int c = 0;
    for (int f = 0; f < NBLK; ++f) if (!flags[f]) inact[c++] = f;
  }
}

// ---------------- x [b][ci][h][w] f32 -> xT [b][h][w][ci] bf16 ----------------
#define XT_PITCH 136
__global__ void k_xt(const float* __restrict__ x, unsigned short* __restrict__ xT){
  __shared__ unsigned short tile[32*XT_PITCH];
  int wc = blockIdx.x, h = blockIdx.y, bi = blockIdx.z;
  int w0 = wc*32;
  int t = threadIdx.x;
  const float* xb = x + (size_t)bi*CIN*HH*WW + (size_t)h*WW + w0;
  #pragma unroll
  for (int it = 0; it < 2; ++it){
    int task = it*256 + t;
    int cp = task>>3, wq = task&7;
    int ci0 = cp*2, wl = wq*4;
    const float* p0 = xb + (size_t)ci0*(HH*WW) + wl;
    float4 a = *(const float4*)p0;
    float4 b = *(const float4*)(p0 + HH*WW);
    *(ushort2*)&tile[(wl+0)*XT_PITCH + ci0] = make_ushort2(f2bf(a.x), f2bf(b.x));
    *(ushort2*)&tile[(wl+1)*XT_PITCH + ci0] = make_ushort2(f2bf(a.y), f2bf(b.y));
    *(ushort2*)&tile[(wl+2)*XT_PITCH + ci0] = make_ushort2(f2bf(a.z), f2bf(b.z));
    *(ushort2*)&tile[(wl+3)*XT_PITCH + ci0] = make_ushort2(f2bf(a.w), f2bf(b.w));
  }
  __syncthreads();
  int w = t>>3, cg = (t&7)*16;
  unsigned short* dst = xT + (((size_t)bi*HH + h)*WW + (w0+w))*CIN + cg;
  *(bfx8*)dst     = *(bfx8*)&tile[w*XT_PITCH + cg];
  *(bfx8*)(dst+8) = *(bfx8*)&tile[w*XT_PITCH + cg + 8];
}

// ---------------- 1x1 GEMM (2-phase pipelined, gload_lds, swizzled LDS)
// MODE 0 = conv1 (active -> h1p bf16 raw + BN1 stat partials)
// MODE 1 = base  (inactive -> out f32 + bd)
template<int MODE>
__global__ __launch_bounds__(256) void k_gemm1(
    const unsigned short* __restrict__ xT, const unsigned short* __restrict__ wgt,
    const int* __restrict__ bidx, const int* __restrict__ inact,
    const float* __restrict__ bd, unsigned short* __restrict__ h1p,
    float* __restrict__ out, float* __restrict__ part){
  __shared__ unsigned short lds[2*4096];   // 2 buf x 512 tasks x 8 hw
  int rg = blockIdx.x, cot = blockIdx.y, z = blockIdx.z;
  int bi, by, bx;
  if (MODE == 0){ bi = bidx[z*3]; by = bidx[z*3+1]; bx = bidx[z*3+2]; }
  else { int fl = inact[z]; bi = fl>>6; by = (fl>>3)&7; bx = fl&7; }
  int t = threadIdx.x, l = t&63, wid = t>>6;
  int wc = wid>>1, wp = wid&1;
  int y0 = rg*4;
  int co_w = cot*128 + wc*64;

  // preload full weight slice for this wave: 16 frags (64 VGPR) -> no global loads in compute
  const unsigned short* wb = wgt + (size_t)(co_w + (l&15))*CIN + ((l>>4)*8);
  bfx8 wfrag[4][4];
  #pragma unroll
  for (int kc = 0; kc < 4; ++kc)
    #pragma unroll
    for (int m = 0; m < 4; ++m)
      wfrag[kc][m] = *(const bfx8*)(wb + kc*32 + (size_t)m*16*CIN);

  // staging setup: 512 tasks, 2 per thread
  const unsigned short* sb[2];
  #pragma unroll
  for (int j = 0; j < 2; ++j){
    int i = j*256 + t;
    int pix = i>>2;
    int slog = (i&3) ^ ((pix>>1)&3);
    sb[j] = xT + (((size_t)bi*HH + (by*BSZ + y0 + (pix>>5)))*WW + (bx*BSZ + (pix&31)))*CIN + slog*8;
  }
  int lo0 = t*8;
  auto stage = [&](int buf, int kc){
    GLOAD16(sb[0] + kc*32, &lds[buf*4096 + lo0]);
    GLOAD16(sb[1] + kc*32, &lds[buf*4096 + 2048 + lo0]);
  };

  int sl = l>>4;
  f32x4 acc[4][4] = {};
  stage(0, 0);
  __syncthreads();
  int cur = 0;
  for (int kc = 0; kc < 4; ++kc){
    if (kc < 3) stage(cur^1, kc+1);
    const unsigned short* lb = &lds[cur*4096];
    #pragma unroll
    for (int f = 0; f < 4; ++f){
      int pix = wp*64 + f*16 + (l&15);
      int sp = sl ^ ((pix>>1)&3);
      bfx8 b = *(const bfx8*)&lb[pix*32 + sp*8];
      acc[0][f] = MFMA(wfrag[kc][0], b, acc[0][f]);
      acc[1][f] = MFMA(wfrag[kc][1], b, acc[1][f]);
      acc[2][f] = MFMA(wfrag[kc][2], b, acc[2][f]);
      acc[3][f] = MFMA(wfrag[kc][3], b, acc[3][f]);
    }
    __syncthreads();
    cur ^= 1;
  }

  #pragma unroll
  for (int m = 0; m < 4; ++m){
    int co = co_w + m*16 + ((l>>4)<<2);
    #pragma unroll
    for (int f = 0; f < 4; ++f){
      int px = wp*64 + f*16 + (l&15);
      int ly = px>>5, lx = px&31;
      if (MODE == 0){
        *(ushort4*)&h1p[((size_t)z*PIX2 + (size_t)(y0+ly+1)*P2 + (lx+1))*COUT + co] =
          make_ushort4(f2bf(acc[m][f][0]), f2bf(acc[m][f][1]),
                       f2bf(acc[m][f][2]), f2bf(acc[m][f][3]));
      } else {
        int gy = by*BSZ + y0 + ly, gx = bx*BSZ + lx;
        #pragma unroll
        for (int j = 0; j < 4; ++j)
          out[(((size_t)bi*COUT + co + j)*HH + gy)*WW + gx] = acc[m][f][j] + bd[co+j];
      }
    }
  }

  if (MODE == 0){
    // BN1 stat partials: sum/sumsq per channel over this block's 128 pixels
    float s_[4][4], q_[4][4];
    #pragma unroll
    for (int m = 0; m < 4; ++m)
      #pragma unroll
      for (int j = 0; j < 4; ++j){
        float s = 0.f, q = 0.f;
        #pragma unroll
        for (int f = 0; f < 4; ++f){ float v = acc[m][f][j]; s += v; q += v*v; }
        s_[m][j] = s; q_[m][j] = q;
      }
    #pragma unroll
    for (int off = 1; off < 16; off <<= 1)
      #pragma unroll
      for (int m = 0; m < 4; ++m)
        #pragma unroll
        for (int j = 0; j < 4; ++j){
          s_[m][j] += __shfl_xor(s_[m][j], off);
          q_[m][j] += __shfl_xor(q_[m][j], off);
        }
    if ((l&15) == 0){
      int grp = z*8 + rg;
      #pragma unroll
      for (int m = 0; m < 4; ++m)
        #pragma unroll
        for (int j = 0; j < 4; ++j){
          int co = co_w + m*16 + ((l>>4)<<2) + j;
          atomicAdd(&part[((size_t)grp*COUT + co)*2],   s_[m][j]);
          atomicAdd(&part[((size_t)grp*COUT + co)*2+1], q_[m][j]);
        }
    }
  }
}

// ---------------- stats finalize: part[grp][co]{s,q} -> st[co]=scale, st[256+co]=shift
__global__ void k_fin(const float* __restrict__ part, const float* __restrict__ g,
                      const float* __restrict__ be, float* __restrict__ st,
                      int ngrp, float inv){
  __shared__ float red[2048];
  int t = threadIdx.x;          // 0..1023
  int co = t & 255, q4 = t >> 8;
  int per = ngrp >> 2;
  float s = 0.f, q = 0.f;
  for (int i = q4*per; i < (q4+1)*per; ++i){
    const float* p = part + ((size_t)i*COUT + co)*2;
    s += p[0]; q += p[1];
  }
  red[t] = s; red[1024+t] = q;
  __syncthreads();
  if (t < 256){
    s = red[t]+red[t+256]+red[t+512]+red[t+768];
    q = red[1024+t]+red[1024+t+256]+red[1024+t+512]+red[1024+t+768];
    float mu = s*inv, var = q*inv - mu*mu;
    float sc = g[t]*rsqrtf(var + 1e-5f);
    st[t] = sc; st[256+t] = be[t] - mu*sc;
  }
}

// ---------------- BN1 apply + ReLU in place on h1p; zero the halo ----------------
__global__ void k_bn1(unsigned short* __restrict__ h1p, const float* __restrict__ st, int total){
  int t = threadIdx.x;
  int ci0 = (t&31)*8;
  float sc[8], tc[8];
  #pragma unroll
  for (int j = 0; j < 8; ++j){ sc[j] = st[ci0+j]; tc[j] = st[256+ci0+j]; }
  #pragma unroll
  for (int it = 0; it < 4; ++it){
    int gpix = blockIdx.x*32 + it*8 + (t>>5);
    if (gpix >= total) continue;
    int n = gpix/PIX2; int p = gpix - n*PIX2;
    int row = p/P2, col = p - row*P2;
    unsigned short* addr = h1p + (size_t)gpix*COUT + ci0;
    if (row >= 1 && row <= 32 && col >= 1 && col <= 32){
      bfx8 v = *(bfx8*)addr;
      unsigned short o[8];
      #pragma unroll
      for (int j = 0; j < 8; ++j){
        float f = bf2f(((unsigned short*)&v)[j]);
        o[j] = f2bf(fmaxf(f*sc[j] + tc[j], 0.f));
      }
      *(bfx8*)addr = *(bfx8*)o;
    } else {
      bfx8 z = {};
      *(bfx8*)addr = z;
    }
  }
}

// ---------------- conv2: 3x3 as 9 accumulated GEMMs, 2-phase pipeline, gload_lds, swizzle.
// h2 raw f32 -> d_out active positions; BN2 stat partials fused into epilogue.
__global__ __launch_bounds__(256) void k_conv2(
    const unsigned short* __restrict__ h1p, const unsigned short* __restrict__ w2t,
    const int* __restrict__ bidx, float* __restrict__ out, float* __restrict__ part){
  __shared__ unsigned short lds[2*6656];   // 2 buf x 832 tasks x 8 hw
  int rg = blockIdx.x, cot = blockIdx.y, n = blockIdx.z;
  int bi = bidx[n*3], by = bidx[n*3+1], bx = bidx[n*3+2];
  int t = threadIdx.x, l = t&63, wid = t>>6;
  int wc = wid>>1, wp = wid&1;
  int y0 = rg*4;
  int co_w = cot*128 + wc*64;
  const unsigned short* tsrc = h1p + ((size_t)n*PIX2 + (size_t)y0*P2)*COUT;

  // staging setup: 816 real tasks (204 pixels x 4 slots), padded to 832
  const unsigned short* sb[4];
  #pragma unroll
  for (int j = 0; j < 4; ++j){
    int i = j*256 + t;
    int pix = i>>2; if (pix > 203) pix = 203;
    int slog = (i&3) ^ ((pix>>1)&3);
    sb[j] = tsrc + (size_t)pix*COUT + slog*8;
  }
  int lo0 = t*8;
  auto stage = [&](int buf, int kc){
    GLOAD16(sb[0] + kc*32, &lds[buf*6656 + lo0]);
    GLOAD16(sb[1] + kc*32, &lds[buf*6656 + 2048 + lo0]);
    GLOAD16(sb[2] + kc*32, &lds[buf*6656 + 4096 + lo0]);
    if (t < 64) GLOAD16(sb[3] + kc*32, &lds[buf*6656 + 6144 + lo0]);
  };

  const unsigned short* wbase = w2t + (size_t)(co_w + (l&15))*COUT + ((l>>4)*8);
  int rb = (wp*2)*34 + (l&15);
  int sl = l>>4;
  f32x4 acc[4][4] = {};

  stage(0, 0);
  __syncthreads();
  int cur = 0;
  for (int kc = 0; kc < 8; ++kc){
    // hoist dy=0 tap-row weights BEFORE issuing next stage (their consumption
    // then doesn't force a vmcnt drain of the staging loads)
    bfx8 a0[3][4];
    #pragma unroll
    for (int dx = 0; dx < 3; ++dx)
      #pragma unroll
      for (int m = 0; m < 4; ++m)
        a0[dx][m] = *(const bfx8*)(wbase + ((size_t)dx*COUT + m*16)*COUT + kc*32);
    if (kc < 7) stage(cur^1, kc+1);
    const unsigned short* lb = &lds[cur*6656];
    #pragma unroll
    for (int dy = 0; dy < 3; ++dy){
      #pragma unroll
      for (int dx = 0; dx < 3; ++dx){
        bfx8 w0, w1, w2, w3;
        if (dy == 0){ w0 = a0[dx][0]; w1 = a0[dx][1]; w2 = a0[dx][2]; w3 = a0[dx][3]; }
        else {
          const unsigned short* wt = wbase + ((size_t)(dy*3+dx)*COUT)*COUT + kc*32;
          w0 = *(const bfx8*)(wt);
          w1 = *(const bfx8*)(wt + 16*COUT);
          w2 = *(const bfx8*)(wt + 32*COUT);
          w3 = *(const bfx8*)(wt + 48*COUT);
        }
        #pragma unroll
        for (int f = 0; f < 4; ++f){
          int pix = rb + ((f>>1) + dy)*34 + (f&1)*16 + dx;
          int sp = sl ^ ((pix>>1)&3);
          bfx8 b = *(const bfx8*)&lb[pix*32 + sp*8];
          acc[0][f] = MFMA(w0, b, acc[0][f]);
          acc[1][f] = MFMA(w1, b, acc[1][f]);
          acc[2][f] = MFMA(w2, b, acc[2][f]);
          acc[3][f] = MFMA(w3, b, acc[3][f]);
        }
      }
    }
    __syncthreads();
    cur ^= 1;
  }

  #pragma unroll
  for (int m = 0; m < 4; ++m){
    int co = co_w + m*16 + ((l>>4)<<2);
    #pragma unroll
    for (int f = 0; f < 4; ++f){
      int r = wp*2 + (f>>1);
      int lx = (f&1)*16 + (l&15);
      int gy = by*BSZ + y0 + r, gx = bx*BSZ + lx;
      #pragma unroll
      for (int j = 0; j < 4; ++j)
        out[(((size_t)bi*COUT + co + j)*HH + gy)*WW + gx] = acc[m][f][j];
    }
  }

  // BN2 stat partials
  float s_[4][4], q_[4][4];
  #pragma unroll
  for (int m = 0; m < 4; ++m)
    #pragma unroll
    for (int j = 0; j < 4; ++j){
      float s = 0.f, q = 0.f;
      #pragma unroll
      for (int f = 0; f < 4; ++f){ float v = acc[m][f][j]; s += v; q += v*v; }
      s_[m][j] = s; q_[m][j] = q;
    }
  #pragma unroll
  for (int off = 1; off < 16; off <<= 1)
    #pragma unroll
    for (int m = 0; m < 4; ++m)
      #pragma unroll
      for (int j = 0; j < 4; ++j){
        s_[m][j] += __shfl_xor(s_[m][j], off);
        q_[m][j] += __shfl_xor(q_[m][j], off);
      }
  if ((l&15) == 0){
    int grp = n*8 + rg;
    #pragma unroll
    for (int m = 0; m < 4; ++m)
      #pragma unroll
      for (int j = 0; j < 4; ++j){
        int co = co_w + m*16 + ((l>>4)<<2) + j;
        atomicAdd(&part[((size_t)grp*COUT + co)*2],   s_[m][j]);
        atomicAdd(&part[((size_t)grp*COUT + co)*2+1], q_[m][j]);
      }
  }
}

// ---------------- BN2 apply + ReLU in place on d_out active blocks ----------------
__global__ void k_bn2(float* __restrict__ out, const int* __restrict__ bidx,
                      const float* __restrict__ st){
  int cq = blockIdx.x, n = blockIdx.y, t = threadIdx.x;
  int bi = bidx[n*3], by = bidx[n*3+1], bx = bidx[n*3+2];
  int px0 = t*4; int ly = px0>>5, lx = px0&31;
  float* base = out + (size_t)bi*COUT*HH*WW + (size_t)(by*BSZ+ly)*WW + bx*BSZ + lx;
  for (int c = 0; c < 64; ++c){
    int co = cq*64 + c;
    float sc = st[co], tc = st[256+co];
    float4* p = (float4*)(base + (size_t)co*HH*WW);
    float4 v = *p;
    v.x = fmaxf(v.x*sc+tc, 0.f); v.y = fmaxf(v.y*sc+tc, 0.f);
    v.z = fmaxf(v.z*sc+tc, 0.f); v.w = fmaxf(v.w*sc+tc, 0.f);
    *p = v;
  }
}

extern "C" void kernel_launch(void* const* d_in, const int* in_sizes, int n_in,
                              void* d_out, int out_size, void* d_ws, size_t ws_size,
                              hipStream_t stream){
  const float* x   = (const float*)d_in[0];
  const float* w1  = (const float*)d_in[1];
  const float* g1  = (const float*)d_in[3];
  const float* be1 = (const float*)d_in[4];
  const float* w2  = (const float*)d_in[5];
  const float* g2  = (const float*)d_in[7];
  const float* be2 = (const float*)d_in[8];
  const float* wd  = (const float*)d_in[9];
  const float* bd  = (const float*)d_in[10];
  const int* bidx  = (const int*)d_in[11];
  float* out = (float*)d_out;
  const int nact = in_sizes[11]/3;     // 128
  const int ninact = NBLK - nact;

  char* wsp = (char*)d_ws;
  size_t off = 0;
  auto carve = [&](size_t bytes)->char*{
    char* p = wsp + off; off += (bytes + 255) & ~(size_t)255; return p;
  };
  unsigned short* xT  = (unsigned short*)carve((size_t)4*HH*WW*CIN*2);
  unsigned short* h1p = (unsigned short*)carve((size_t)nact*PIX2*COUT*2 + 4096);
  unsigned short* w1b = (unsigned short*)carve((size_t)COUT*CIN*2);
  unsigned short* wdb = (unsigned short*)carve((size_t)COUT*CIN*2);
  unsigned short* w2t = (unsigned short*)carve((size_t)9*COUT*COUT*2);
  float* s1t1  = (float*)carve(512*4);
  float* s2t2  = (float*)carve(512*4);
  float* part1 = (float*)carve((size_t)nact*8*COUT*2*4);
  float* part2 = (float*)carve((size_t)nact*8*COUT*2*4);
  int* flags   = (int*)carve(NBLK*4);
  int* inact   = (int*)carve(NBLK*4);

  hipMemsetAsync(flags, 0, NBLK*4, stream);
  hipMemsetAsync(part1, 0, (size_t)nact*8*COUT*2*4, stream);
  hipMemsetAsync(part2, 0, (size_t)nact*8*COUT*2*4, stream);
  k_lists<<<1, 256, 0, stream>>>(bidx, nact, flags, inact);
  k_prep<<<2304, 256, 0, stream>>>(w1, wd, w2, w1b, wdb, w2t);
  k_xt<<<dim3(8, HH, 4), 256, 0, stream>>>(x, xT);
  k_gemm1<0><<<dim3(8, 2, nact), 256, 0, stream>>>(xT, w1b, bidx, inact, bd, h1p, out, part1);
  k_fin<<<1, 1024, 0, stream>>>(part1, g1, be1, s1t1, nact*8, 1.0f/((float)nact*1024.0f));
  {
    int total = nact*PIX2;
    k_bn1<<<(total + 31)/32, 256, 0, stream>>>(h1p, s1t1, total);
  }
  k_conv2<<<dim3(8, 2, nact), 256, 0, stream>>>(h1p, w2t, bidx, out, part2);
  k_fin<<<1, 1024, 0, stream>>>(part2, g2, be2, s2t2, nact*8, 1.0f/((float)nact*1024.0f));
  if (ninact > 0)
    k_gemm1<1><<<dim3(8, 2, ninact), 256, 0, stream>>>(xT, wdb, bidx, inact, bd, h1p, out, part1);
  k_bn2<<<dim3(4, nact), 256, 0, stream>>>(out, bidx, s2t2);
}

// Round 3
// 606.164 us; speedup vs baseline: 1.4825x; 1.2503x over previous
//
#include <hip/hip_runtime.h>
#include <stdint.h>

#define CIN  128
#define COUT 256
#define HH   256
#define WW   256
#define BSZ  32
#define HB   8
#define WB   8
#define NBLK 256
#define P2   34          // padded block dim (32 + halo)
#define PIX2 1156        // 34*34

typedef __attribute__((ext_vector_type(8))) short bfx8;
typedef __attribute__((ext_vector_type(4))) float f32x4;

#define MFMA(a,b,c) __builtin_amdgcn_mfma_f32_16x16x32_bf16((a),(b),(c),0,0,0)

typedef const __attribute__((address_space(1))) unsigned int gu32;
typedef __attribute__((address_space(3))) unsigned int lu32;
#define GLOAD16(g, p) __builtin_amdgcn_global_load_lds((gu32*)(g), (lu32*)(p), 16, 0, 0)

static __device__ __forceinline__ float bf2f(unsigned short u){
  union { unsigned int i; float f; } v; v.i = ((unsigned int)u)<<16; return v.f;
}
static __device__ __forceinline__ unsigned short f2bf(float f){
  union { float f; unsigned int i; } v; v.f = f;
  unsigned int r = v.i + 0x7fffu + ((v.i>>16)&1u);
  return (unsigned short)(r>>16);
}

// ---------------- prep: weights -> bf16 (w2 transposed to [tap][co][ci]) ----------------
__global__ void k_prep(const float* __restrict__ w1, const float* __restrict__ wd,
                       const float* __restrict__ w2,
                       unsigned short* __restrict__ w1b, unsigned short* __restrict__ wdb,
                       unsigned short* __restrict__ w2t){
  int i = blockIdx.x*256 + threadIdx.x;
  if (i < COUT*CIN){ w1b[i] = f2bf(w1[i]); wdb[i] = f2bf(wd[i]); }
  if (i < COUT*COUT*9){
    int co = i/2304, r = i - co*2304;
    int ci = r/9,   tp = r - ci*9;
    w2t[((size_t)tp*COUT + co)*COUT + ci] = f2bf(w2[i]);
  }
}

// ---------------- active flags + inactive block list ----------------
__global__ void k_lists(const int* __restrict__ bidx, int nact,
                        int* __restrict__ flags, int* __restrict__ inact){
  int t = threadIdx.x;
  if (t < nact){
    int f = bidx[t*3]*(HB*WB) + bidx[t*3+1]*WB + bidx[t*3+2];
    flags[f] = 1;
  }
  __syncthreads();
  if (t == 0){
    int c = 0;
    for (int f = 0; f < NBLK; ++f) if (!flags[f]) inact[c++] = f;
  }
}

// ---------------- 1x1 GEMM reading x (f32) directly, transpose-in-register staging.
// MODE 0 = conv1 (active -> h1p bf16 raw + BN1 stat partials)
// MODE 1 = base  (inactive -> out f32 + bd)
template<int MODE>
__global__ __launch_bounds__(256) void k_gemm1(
    const float* __restrict__ x, const unsigned short* __restrict__ wgt,
    const int* __restrict__ bidx, const int* __restrict__ inact,
    const float* __restrict__ bd, unsigned short* __restrict__ h1p,
    float* __restrict__ out, float* __restrict__ part){
  __shared__ unsigned short lds[2*5120];   // 2 buf x 128 px x pitch 40
  int rg = blockIdx.x, cot = blockIdx.y, z = blockIdx.z;
  int bi, by, bx;
  if (MODE == 0){ bi = bidx[z*3]; by = bidx[z*3+1]; bx = bidx[z*3+2]; }
  else { int fl = inact[z]; bi = fl>>6; by = (fl>>3)&7; bx = fl&7; }
  int t = threadIdx.x, l = t&63, wid = t>>6;
  int wc = wid>>1, wp = wid&1;
  int y0 = rg*4;
  int co_w = cot*128 + wc*64;

  // full weight slice in registers (16 frags = 64 VGPR), issued before any stage load
  const unsigned short* wb = wgt + (size_t)(co_w + (l&15))*CIN + ((l>>4)*8);
  bfx8 wfrag[4][4];
  #pragma unroll
  for (int kc = 0; kc < 4; ++kc)
    #pragma unroll
    for (int m = 0; m < 4; ++m)
      wfrag[kc][m] = *(const bfx8*)(wb + kc*32 + (size_t)m*16*CIN);

  // x staging: units u = t, 256+t : ci_pair = u>>5 (x2 ci), pxg = u&31 (x4 px)
  const float* xb = x + (size_t)bi*CIN*HH*WW + (size_t)(by*BSZ + y0)*WW + bx*BSZ;
  float4 ra[2], rb_[2];
  auto ldreg = [&](int kc){
    #pragma unroll
    for (int j = 0; j < 2; ++j){
      int u = j*256 + t;
      int ci0 = (u>>5)*2 + kc*32;
      int p = (u&31)*4;
      const float* s = xb + (size_t)ci0*(HH*WW) + (p>>5)*WW + (p&31);
      ra[j]  = *(const float4*)s;
      rb_[j] = *(const float4*)(s + HH*WW);
    }
  };
  auto wrlds = [&](int buf){
    #pragma unroll
    for (int j = 0; j < 2; ++j){
      int u = j*256 + t;
      int ci0 = (u>>5)*2;
      int p = (u&31)*4;
      unsigned short* d = &lds[buf*5120 + ci0];
      *(ushort2*)&d[(p+0)*40] = make_ushort2(f2bf(ra[j].x), f2bf(rb_[j].x));
      *(ushort2*)&d[(p+1)*40] = make_ushort2(f2bf(ra[j].y), f2bf(rb_[j].y));
      *(ushort2*)&d[(p+2)*40] = make_ushort2(f2bf(ra[j].z), f2bf(rb_[j].z));
      *(ushort2*)&d[(p+3)*40] = make_ushort2(f2bf(ra[j].w), f2bf(rb_[j].w));
    }
  };

  f32x4 acc[4][4] = {};
  ldreg(0);
  for (int kc = 0; kc < 4; ++kc){
    wrlds(kc&1);
    if (kc < 3) ldreg(kc+1);   // in flight across barrier+compute
    __syncthreads();
    const unsigned short* lb = &lds[(kc&1)*5120];
    #pragma unroll
    for (int f = 0; f < 4; ++f){
      bfx8 b = *(const bfx8*)&lb[(wp*64 + f*16 + (l&15))*40 + (l>>4)*8];
      acc[0][f] = MFMA(wfrag[kc][0], b, acc[0][f]);
      acc[1][f] = MFMA(wfrag[kc][1], b, acc[1][f]);
      acc[2][f] = MFMA(wfrag[kc][2], b, acc[2][f]);
      acc[3][f] = MFMA(wfrag[kc][3], b, acc[3][f]);
    }
    // single barrier per phase is safe: passing barrier(kc) implies all waves
    // finished compute(kc-1), so writing buf[(kc+1)&1] next iteration is race-free.
  }

  #pragma unroll
  for (int m = 0; m < 4; ++m){
    int co = co_w + m*16 + ((l>>4)<<2);
    #pragma unroll
    for (int f = 0; f < 4; ++f){
      int px = wp*64 + f*16 + (l&15);
      int ly = px>>5, lx = px&31;
      if (MODE == 0){
        *(ushort4*)&h1p[((size_t)z*PIX2 + (size_t)(y0+ly+1)*P2 + (lx+1))*COUT + co] =
          make_ushort4(f2bf(acc[m][f][0]), f2bf(acc[m][f][1]),
                       f2bf(acc[m][f][2]), f2bf(acc[m][f][3]));
      } else {
        int gy = by*BSZ + y0 + ly, gx = bx*BSZ + lx;
        #pragma unroll
        for (int j = 0; j < 4; ++j)
          out[(((size_t)bi*COUT + co + j)*HH + gy)*WW + gx] = acc[m][f][j] + bd[co+j];
      }
    }
  }

  if (MODE == 0){
    float s_[4][4], q_[4][4];
    #pragma unroll
    for (int m = 0; m < 4; ++m)
      #pragma unroll
      for (int j = 0; j < 4; ++j){
        float s = 0.f, q = 0.f;
        #pragma unroll
        for (int f = 0; f < 4; ++f){ float v = acc[m][f][j]; s += v; q += v*v; }
        s_[m][j] = s; q_[m][j] = q;
      }
    #pragma unroll
    for (int off = 1; off < 16; off <<= 1)
      #pragma unroll
      for (int m = 0; m < 4; ++m)
        #pragma unroll
        for (int j = 0; j < 4; ++j){
          s_[m][j] += __shfl_xor(s_[m][j], off);
          q_[m][j] += __shfl_xor(q_[m][j], off);
        }
    if ((l&15) == 0){
      int grp = z & 15;
      #pragma unroll
      for (int m = 0; m < 4; ++m)
        #pragma unroll
        for (int j = 0; j < 4; ++j){
          int co = co_w + m*16 + ((l>>4)<<2) + j;
          atomicAdd(&part[((size_t)grp*COUT + co)*2],   s_[m][j]);
          atomicAdd(&part[((size_t)grp*COUT + co)*2+1], q_[m][j]);
        }
    }
  }
}

// ---------------- stats finalize: 16 partial groups -> st[co]=scale, st[256+co]=shift
__global__ void k_fin(const float* __restrict__ part, const float* __restrict__ g,
                      const float* __restrict__ be, float* __restrict__ st, float inv){
  int t = threadIdx.x;   // 256
  float s = 0.f, q = 0.f;
  #pragma unroll
  for (int gi = 0; gi < 16; ++gi){
    s += part[((size_t)gi*COUT + t)*2];
    q += part[((size_t)gi*COUT + t)*2+1];
  }
  float mu = s*inv, var = q*inv - mu*mu;
  float sc = g[t]*rsqrtf(var + 1e-5f);
  st[t] = sc; st[256+t] = be[t] - mu*sc;
}

// ---------------- BN1 apply + ReLU in place on h1p; zero the halo ----------------
__global__ void k_bn1(unsigned short* __restrict__ h1p, const float* __restrict__ st, int total){
  int t = threadIdx.x;
  int ci0 = (t&31)*8;
  float sc[8], tc[8];
  #pragma unroll
  for (int j = 0; j < 8; ++j){ sc[j] = st[ci0+j]; tc[j] = st[256+ci0+j]; }
  #pragma unroll
  for (int it = 0; it < 4; ++it){
    int gpix = blockIdx.x*32 + it*8 + (t>>5);
    if (gpix >= total) continue;
    int n = gpix/PIX2; int p = gpix - n*PIX2;
    int row = p/P2, col = p - row*P2;
    unsigned short* addr = h1p + (size_t)gpix*COUT + ci0;
    if (row >= 1 && row <= 32 && col >= 1 && col <= 32){
      bfx8 v = *(bfx8*)addr;
      unsigned short o[8];
      #pragma unroll
      for (int j = 0; j < 8; ++j){
        float f = bf2f(((unsigned short*)&v)[j]);
        o[j] = f2bf(fmaxf(f*sc[j] + tc[j], 0.f));
      }
      *(bfx8*)addr = *(bfx8*)o;
    } else {
      bfx8 z = {};
      *(bfx8*)addr = z;
    }
  }
}

// ---------------- conv2: 3x3 as 9 accumulated GEMMs.
// 8 waves, 8-row tile (10x34 staged pixels), weights issued BEFORE stage loads so
// vmcnt in-order retirement never drains the gload_lds prefetch mid-compute.
__global__ __launch_bounds__(512) void k_conv2(
    const unsigned short* __restrict__ h1p, const unsigned short* __restrict__ w2t,
    const int* __restrict__ bidx, float* __restrict__ out, float* __restrict__ part){
  __shared__ unsigned short lds[2*10880];   // 2 buf x 340 px x 32 ci
  int rg = blockIdx.x, cot = blockIdx.y, n = blockIdx.z;
  int bi = bidx[n*3], by = bidx[n*3+1], bx = bidx[n*3+2];
  int t = threadIdx.x, l = t&63, wid = t>>6;
  int wc = wid>>2, wp = wid&3;            // 2 co-groups x 4 px-row-pair groups
  int y0 = rg*8;
  int co_w = cot*128 + wc*64;
  const unsigned short* tsrc = h1p + ((size_t)n*PIX2 + (size_t)y0*P2)*COUT;

  // stage task setup: 1360 tasks (340 px x 4 ci-octet slots), 3 rounds of 512
  int offq[3]; bool actq[3];
  #pragma unroll
  for (int it = 0; it < 3; ++it){
    int t3 = it*512 + t;
    int pix = t3>>2;
    actq[it] = (pix < 340);
    if (pix > 339) pix = 339;
    int slog = (t3&3) ^ ((pix>>1)&3);
    offq[it] = pix*COUT + slog*8;
  }
  auto stage = [&](int buf, int kc){
    #pragma unroll
    for (int it = 0; it < 3; ++it){
      if (actq[it])
        GLOAD16(tsrc + offq[it] + kc*32, &lds[buf*10880 + it*4096 + t*8]);
    }
  };

  const unsigned short* wbase = w2t + (size_t)(co_w + (l&15))*COUT + ((l>>4)*8);
  int rb = (wp*2)*34 + (l&15);
  int sl = l>>4;
  f32x4 acc[4][4] = {};

  stage(0, 0);
  __syncthreads();
  int cur = 0;
  for (int kc = 0; kc < 8; ++kc){
    // dy=0,1 weights (24 frags) issued BEFORE the stage loads
    bfx8 wf0[3][4], wf1[3][4];
    #pragma unroll
    for (int dx = 0; dx < 3; ++dx)
      #pragma unroll
      for (int m = 0; m < 4; ++m){
        wf0[dx][m] = *(const bfx8*)(wbase + ((size_t)(dx      )*COUT + m*16)*COUT + kc*32);
        wf1[dx][m] = *(const bfx8*)(wbase + ((size_t)(3 + dx  )*COUT + m*16)*COUT + kc*32);
      }
    if (kc < 7) stage(cur^1, kc+1);
    const unsigned short* lb = &lds[cur*10880];

    // dy = 0
    #pragma unroll
    for (int dx = 0; dx < 3; ++dx){
      #pragma unroll
      for (int f = 0; f < 4; ++f){
        int pix = rb + (f>>1)*34 + (f&1)*16 + dx;
        int sp = sl ^ ((pix>>1)&3);
        bfx8 b = *(const bfx8*)&lb[pix*32 + sp*8];
        acc[0][f] = MFMA(wf0[dx][0], b, acc[0][f]);
        acc[1][f] = MFMA(wf0[dx][1], b, acc[1][f]);
        acc[2][f] = MFMA(wf0[dx][2], b, acc[2][f]);
        acc[3][f] = MFMA(wf0[dx][3], b, acc[3][f]);
      }
    }
    // dy=2 weights issued here: their wait drains stage, but ~2/3 of compute
    // has passed by consumption time, so the HBM latency is covered.
    bfx8 wf2[3][4];
    #pragma unroll
    for (int dx = 0; dx < 3; ++dx)
      #pragma unroll
      for (int m = 0; m < 4; ++m)
        wf2[dx][m] = *(const bfx8*)(wbase + ((size_t)(6 + dx)*COUT + m*16)*COUT + kc*32);
    // dy = 1
    #pragma unroll
    for (int dx = 0; dx < 3; ++dx){
      #pragma unroll
      for (int f = 0; f < 4; ++f){
        int pix = rb + ((f>>1) + 1)*34 + (f&1)*16 + dx;
        int sp = sl ^ ((pix>>1)&3);
        bfx8 b = *(const bfx8*)&lb[pix*32 + sp*8];
        acc[0][f] = MFMA(wf1[dx][0], b, acc[0][f]);
        acc[1][f] = MFMA(wf1[dx][1], b, acc[1][f]);
        acc[2][f] = MFMA(wf1[dx][2], b, acc[2][f]);
        acc[3][f] = MFMA(wf1[dx][3], b, acc[3][f]);
      }
    }
    // dy = 2
    #pragma unroll
    for (int dx = 0; dx < 3; ++dx){
      #pragma unroll
      for (int f = 0; f < 4; ++f){
        int pix = rb + ((f>>1) + 2)*34 + (f&1)*16 + dx;
        int sp = sl ^ ((pix>>1)&3);
        bfx8 b = *(const bfx8*)&lb[pix*32 + sp*8];
        acc[0][f] = MFMA(wf2[dx][0], b, acc[0][f]);
        acc[1][f] = MFMA(wf2[dx][1], b, acc[1][f]);
        acc[2][f] = MFMA(wf2[dx][2], b, acc[2][f]);
        acc[3][f] = MFMA(wf2[dx][3], b, acc[3][f]);
      }
    }
    __syncthreads();
    cur ^= 1;
  }

  #pragma unroll
  for (int m = 0; m < 4; ++m){
    int co = co_w + m*16 + ((l>>4)<<2);
    #pragma unroll
    for (int f = 0; f < 4; ++f){
      int r = wp*2 + (f>>1);
      int lx = (f&1)*16 + (l&15);
      int gy = by*BSZ + y0 + r, gx = bx*BSZ + lx;
      #pragma unroll
      for (int j = 0; j < 4; ++j)
        out[(((size_t)bi*COUT + co + j)*HH + gy)*WW + gx] = acc[m][f][j];
    }
  }

  // BN2 stat partials
  float s_[4][4], q_[4][4];
  #pragma unroll
  for (int m = 0; m < 4; ++m)
    #pragma unroll
    for (int j = 0; j < 4; ++j){
      float s = 0.f, q = 0.f;
      #pragma unroll
      for (int f = 0; f < 4; ++f){ float v = acc[m][f][j]; s += v; q += v*v; }
      s_[m][j] = s; q_[m][j] = q;
    }
  #pragma unroll
  for (int off = 1; off < 16; off <<= 1)
    #pragma unroll
    for (int m = 0; m < 4; ++m)
      #pragma unroll
      for (int j = 0; j < 4; ++j){
        s_[m][j] += __shfl_xor(s_[m][j], off);
        q_[m][j] += __shfl_xor(q_[m][j], off);
      }
  if ((l&15) == 0){
    int grp = n & 15;
    #pragma unroll
    for (int m = 0; m < 4; ++m)
      #pragma unroll
      for (int j = 0; j < 4; ++j){
        int co = co_w + m*16 + ((l>>4)<<2) + j;
        atomicAdd(&part[((size_t)grp*COUT + co)*2],   s_[m][j]);
        atomicAdd(&part[((size_t)grp*COUT + co)*2+1], q_[m][j]);
      }
  }
}

// ---------------- BN2 apply + ReLU in place on d_out active blocks ----------------
__global__ void k_bn2(float* __restrict__ out, const int* __restrict__ bidx,
                      const float* __restrict__ st){
  int cq = blockIdx.x, n = blockIdx.y, t = threadIdx.x;
  int bi = bidx[n*3], by = bidx[n*3+1], bx = bidx[n*3+2];
  int px0 = t*4; int ly = px0>>5, lx = px0&31;
  float* base = out + (size_t)bi*COUT*HH*WW + (size_t)(by*BSZ+ly)*WW + bx*BSZ + lx;
  for (int c = 0; c < 64; ++c){
    int co = cq*64 + c;
    float sc = st[co], tc = st[256+co];
    float4* p = (float4*)(base + (size_t)co*HH*WW);
    float4 v = *p;
    v.x = fmaxf(v.x*sc+tc, 0.f); v.y = fmaxf(v.y*sc+tc, 0.f);
    v.z = fmaxf(v.z*sc+tc, 0.f); v.w = fmaxf(v.w*sc+tc, 0.f);
    *p = v;
  }
}

extern "C" void kernel_launch(void* const* d_in, const int* in_sizes, int n_in,
                              void* d_out, int out_size, void* d_ws, size_t ws_size,
                              hipStream_t stream){
  const float* x   = (const float*)d_in[0];
  const float* w1  = (const float*)d_in[1];
  const float* g1  = (const float*)d_in[3];
  const float* be1 = (const float*)d_in[4];
  const float* w2  = (const float*)d_in[5];
  const float* g2  = (const float*)d_in[7];
  const float* be2 = (const float*)d_in[8];
  const float* wd  = (const float*)d_in[9];
  const float* bd  = (const float*)d_in[10];
  const int* bidx  = (const int*)d_in[11];
  float* out = (float*)d_out;
  const int nact = in_sizes[11]/3;     // 128
  const int ninact = NBLK - nact;

  char* wsp = (char*)d_ws;
  size_t off = 0;
  auto carve = [&](size_t bytes)->char*{
    char* p = wsp + off; off += (bytes + 255) & ~(size_t)255; return p;
  };
  unsigned short* h1p = (unsigned short*)carve((size_t)nact*PIX2*COUT*2 + 4096);
  unsigned short* w1b = (unsigned short*)carve((size_t)COUT*CIN*2);
  unsigned short* wdb = (unsigned short*)carve((size_t)COUT*CIN*2);
  unsigned short* w2t = (unsigned short*)carve((size_t)9*COUT*COUT*2);
  float* s1t1  = (float*)carve(512*4);
  float* s2t2  = (float*)carve(512*4);
  float* part1 = (float*)carve((size_t)16*COUT*2*4);
  float* part2 = (float*)carve((size_t)16*COUT*2*4);
  int* flags   = (int*)carve(NBLK*4);
  int* inact   = (int*)carve(NBLK*4);

  hipMemsetAsync(flags, 0, NBLK*4, stream);
  hipMemsetAsync(part1, 0, (size_t)16*COUT*2*4, stream);
  hipMemsetAsync(part2, 0, (size_t)16*COUT*2*4, stream);
  k_lists<<<1, 256, 0, stream>>>(bidx, nact, flags, inact);
  k_prep<<<2304, 256, 0, stream>>>(w1, wd, w2, w1b, wdb, w2t);
  k_gemm1<0><<<dim3(8, 2, nact), 256, 0, stream>>>(x, w1b, bidx, inact, bd, h1p, out, part1);
  k_fin<<<1, 256, 0, stream>>>(part1, g1, be1, s1t1, 1.0f/((float)nact*1024.0f));
  {
    int total = nact*PIX2;
    k_bn1<<<(total + 31)/32, 256, 0, stream>>>(h1p, s1t1, total);
  }
  k_conv2<<<dim3(4, 2, nact), 512, 0, stream>>>(h1p, w2t, bidx, out, part2);
  k_fin<<<1, 256, 0, stream>>>(part2, g2, be2, s2t2, 1.0f/((float)nact*1024.0f));
  if (ninact > 0)
    k_gemm1<1><<<dim3(8, 2, ninact), 256, 0, stream>>>(x, wdb, bidx, inact, bd, h1p, out, part1);
  k_bn2<<<dim3(4, nact), 256, 0, stream>>>(out, bidx, s2t2);
}

// Round 4
// 458.228 us; speedup vs baseline: 1.9612x; 1.3228x over previous
//
#include <hip/hip_runtime.h>
#include <stdint.h>

#define CIN  128
#define COUT 256
#define HH   256
#define WW   256
#define BSZ  32
#define HB   8
#define WB   8
#define NBLK 256
#define P2   34          // padded block dim (32 + halo)
#define PIX2 1156        // 34*34

typedef __attribute__((ext_vector_type(8))) short bfx8;
typedef __attribute__((ext_vector_type(4))) float f32x4;

#define MFMA(a,b,c) __builtin_amdgcn_mfma_f32_16x16x32_bf16((a),(b),(c),0,0,0)

typedef const __attribute__((address_space(1))) unsigned int gu32;
typedef __attribute__((address_space(3))) unsigned int lu32;
#define GLOAD16(g, p) __builtin_amdgcn_global_load_lds((gu32*)(g), (lu32*)(p), 16, 0, 0)

static __device__ __forceinline__ float bf2f(unsigned short u){
  union { unsigned int i; float f; } v; v.i = ((unsigned int)u)<<16; return v.f;
}
static __device__ __forceinline__ unsigned short f2bf(float f){
  union { float f; unsigned int i; } v; v.f = f;
  unsigned int r = v.i + 0x7fffu + ((v.i>>16)&1u);
  return (unsigned short)(r>>16);
}

// ---------------- prep: weights -> bf16 (w2 transposed to [tap][co][ci]) ----------------
__global__ void k_prep(const float* __restrict__ w1, const float* __restrict__ wd,
                       const float* __restrict__ w2,
                       unsigned short* __restrict__ w1b, unsigned short* __restrict__ wdb,
                       unsigned short* __restrict__ w2t){
  int i = blockIdx.x*256 + threadIdx.x;
  if (i < COUT*CIN){ w1b[i] = f2bf(w1[i]); wdb[i] = f2bf(wd[i]); }
  if (i < COUT*COUT*9){
    int co = i/2304, r = i - co*2304;
    int ci = r/9,   tp = r - ci*9;
    w2t[((size_t)tp*COUT + co)*COUT + ci] = f2bf(w2[i]);
  }
}

// ---------------- active flags + inactive block list ----------------
__global__ void k_lists(const int* __restrict__ bidx, int nact,
                        int* __restrict__ flags, int* __restrict__ inact){
  int t = threadIdx.x;
  if (t < nact){
    int f = bidx[t*3]*(HB*WB) + bidx[t*3+1]*WB + bidx[t*3+2];
    flags[f] = 1;
  }
  __syncthreads();
  if (t == 0){
    int c = 0;
    for (int f = 0; f < NBLK; ++f) if (!flags[f]) inact[c++] = f;
  }
}

// ---------------- 1x1 GEMM reading x (f32) directly, transpose-in-register staging.
// MODE 0 = conv1 (active -> h1p bf16 raw + BN1 stat partials)
// MODE 1 = base  (inactive -> out f32 + bd)
template<int MODE>
__global__ __launch_bounds__(256) void k_gemm1(
    const float* __restrict__ x, const unsigned short* __restrict__ wgt,
    const int* __restrict__ bidx, const int* __restrict__ inact,
    const float* __restrict__ bd, unsigned short* __restrict__ h1p,
    float* __restrict__ out, float* __restrict__ part){
  __shared__ unsigned short lds[2*5120];   // 2 buf x 128 px x pitch 40
  int rg = blockIdx.x, cot = blockIdx.y, z = blockIdx.z;
  int bi, by, bx;
  if (MODE == 0){ bi = bidx[z*3]; by = bidx[z*3+1]; bx = bidx[z*3+2]; }
  else { int fl = inact[z]; bi = fl>>6; by = (fl>>3)&7; bx = fl&7; }
  int t = threadIdx.x, l = t&63, wid = t>>6;
  int wc = wid>>1, wp = wid&1;
  int y0 = rg*4;
  int co_w = cot*128 + wc*64;

  // full weight slice in registers (16 frags = 64 VGPR), issued before any stage load
  const unsigned short* wb = wgt + (size_t)(co_w + (l&15))*CIN + ((l>>4)*8);
  bfx8 wfrag[4][4];
  #pragma unroll
  for (int kc = 0; kc < 4; ++kc)
    #pragma unroll
    for (int m = 0; m < 4; ++m)
      wfrag[kc][m] = *(const bfx8*)(wb + kc*32 + (size_t)m*16*CIN);

  // x staging: units u = t, 256+t : ci_pair = u>>5 (x2 ci), pxg = u&31 (x4 px)
  const float* xb = x + (size_t)bi*CIN*HH*WW + (size_t)(by*BSZ + y0)*WW + bx*BSZ;
  float4 ra[2], rb_[2];
  auto ldreg = [&](int kc){
    #pragma unroll
    for (int j = 0; j < 2; ++j){
      int u = j*256 + t;
      int ci0 = (u>>5)*2 + kc*32;
      int p = (u&31)*4;
      const float* s = xb + (size_t)ci0*(HH*WW) + (p>>5)*WW + (p&31);
      ra[j]  = *(const float4*)s;
      rb_[j] = *(const float4*)(s + HH*WW);
    }
  };
  auto wrlds = [&](int buf){
    #pragma unroll
    for (int j = 0; j < 2; ++j){
      int u = j*256 + t;
      int ci0 = (u>>5)*2;
      int p = (u&31)*4;
      unsigned short* d = &lds[buf*5120 + ci0];
      *(ushort2*)&d[(p+0)*40] = make_ushort2(f2bf(ra[j].x), f2bf(rb_[j].x));
      *(ushort2*)&d[(p+1)*40] = make_ushort2(f2bf(ra[j].y), f2bf(rb_[j].y));
      *(ushort2*)&d[(p+2)*40] = make_ushort2(f2bf(ra[j].z), f2bf(rb_[j].z));
      *(ushort2*)&d[(p+3)*40] = make_ushort2(f2bf(ra[j].w), f2bf(rb_[j].w));
    }
  };

  f32x4 acc[4][4] = {};
  ldreg(0);
  for (int kc = 0; kc < 4; ++kc){
    wrlds(kc&1);
    if (kc < 3) ldreg(kc+1);   // in flight across barrier+compute
    __syncthreads();
    const unsigned short* lb = &lds[(kc&1)*5120];
    #pragma unroll
    for (int f = 0; f < 4; ++f){
      bfx8 b = *(const bfx8*)&lb[(wp*64 + f*16 + (l&15))*40 + (l>>4)*8];
      acc[0][f] = MFMA(wfrag[kc][0], b, acc[0][f]);
      acc[1][f] = MFMA(wfrag[kc][1], b, acc[1][f]);
      acc[2][f] = MFMA(wfrag[kc][2], b, acc[2][f]);
      acc[3][f] = MFMA(wfrag[kc][3], b, acc[3][f]);
    }
  }

  #pragma unroll
  for (int m = 0; m < 4; ++m){
    int co = co_w + m*16 + ((l>>4)<<2);
    #pragma unroll
    for (int f = 0; f < 4; ++f){
      int px = wp*64 + f*16 + (l&15);
      int ly = px>>5, lx = px&31;
      if (MODE == 0){
        *(ushort4*)&h1p[((size_t)z*PIX2 + (size_t)(y0+ly+1)*P2 + (lx+1))*COUT + co] =
          make_ushort4(f2bf(acc[m][f][0]), f2bf(acc[m][f][1]),
                       f2bf(acc[m][f][2]), f2bf(acc[m][f][3]));
      } else {
        int gy = by*BSZ + y0 + ly, gx = bx*BSZ + lx;
        #pragma unroll
        for (int j = 0; j < 4; ++j)
          out[(((size_t)bi*COUT + co + j)*HH + gy)*WW + gx] = acc[m][f][j] + bd[co+j];
      }
    }
  }

  if (MODE == 0){
    float s_[4][4], q_[4][4];
    #pragma unroll
    for (int m = 0; m < 4; ++m)
      #pragma unroll
      for (int j = 0; j < 4; ++j){
        float s = 0.f, q = 0.f;
        #pragma unroll
        for (int f = 0; f < 4; ++f){ float v = acc[m][f][j]; s += v; q += v*v; }
        s_[m][j] = s; q_[m][j] = q;
      }
    #pragma unroll
    for (int off = 1; off < 16; off <<= 1)
      #pragma unroll
      for (int m = 0; m < 4; ++m)
        #pragma unroll
        for (int j = 0; j < 4; ++j){
          s_[m][j] += __shfl_xor(s_[m][j], off);
          q_[m][j] += __shfl_xor(q_[m][j], off);
        }
    if ((l&15) == 0){
      int grp = z & 15;
      #pragma unroll
      for (int m = 0; m < 4; ++m)
        #pragma unroll
        for (int j = 0; j < 4; ++j){
          int co = co_w + m*16 + ((l>>4)<<2) + j;
          atomicAdd(&part[((size_t)grp*COUT + co)*2],   s_[m][j]);
          atomicAdd(&part[((size_t)grp*COUT + co)*2+1], q_[m][j]);
        }
    }
  }
}

// ---------------- stats finalize: 16 partial groups -> st[co]=scale, st[256+co]=shift
__global__ void k_fin(const float* __restrict__ part, const float* __restrict__ g,
                      const float* __restrict__ be, float* __restrict__ st, float inv){
  int t = threadIdx.x;   // 256
  float s = 0.f, q = 0.f;
  #pragma unroll
  for (int gi = 0; gi < 16; ++gi){
    s += part[((size_t)gi*COUT + t)*2];
    q += part[((size_t)gi*COUT + t)*2+1];
  }
  float mu = s*inv, var = q*inv - mu*mu;
  float sc = g[t]*rsqrtf(var + 1e-5f);
  st[t] = sc; st[256+t] = be[t] - mu*sc;
}

// ---------------- BN1 apply + ReLU in place on h1p; zero the halo ----------------
__global__ void k_bn1(unsigned short* __restrict__ h1p, const float* __restrict__ st, int total){
  int t = threadIdx.x;
  int ci0 = (t&31)*8;
  float sc[8], tc[8];
  #pragma unroll
  for (int j = 0; j < 8; ++j){ sc[j] = st[ci0+j]; tc[j] = st[256+ci0+j]; }
  #pragma unroll
  for (int it = 0; it < 4; ++it){
    int gpix = blockIdx.x*32 + it*8 + (t>>5);
    if (gpix >= total) continue;
    int n = gpix/PIX2; int p = gpix - n*PIX2;
    int row = p/P2, col = p - row*P2;
    unsigned short* addr = h1p + (size_t)gpix*COUT + ci0;
    if (row >= 1 && row <= 32 && col >= 1 && col <= 32){
      bfx8 v = *(bfx8*)addr;
      unsigned short o[8];
      #pragma unroll
      for (int j = 0; j < 8; ++j){
        float f = bf2f(((unsigned short*)&v)[j]);
        o[j] = f2bf(fmaxf(f*sc[j] + tc[j], 0.f));
      }
      *(bfx8*)addr = *(bfx8*)o;
    } else {
      bfx8 z = {};
      *(bfx8*)addr = z;
    }
  }
}

// ---------------- conv2 as GEMM: C[256co][256px] += W[256co][K=2304] * Im2col[K][256px]
// K tap-major (9 taps x 4 ci64-chunks = 36 K-steps of 64). A and B both LDS-staged
// via global_load_lds, 128KB double-buffered, XOR-slot swizzle, 2-phase schedule.
// 8 waves = 2M x 4N, wave C-tile 128co x 64px, acc[8][4].
__global__ __launch_bounds__(512, 2) void k_conv2(
    const unsigned short* __restrict__ h1p, const unsigned short* __restrict__ w2t,
    const int* __restrict__ bidx, float* __restrict__ out, float* __restrict__ part){
  __shared__ unsigned short lds[65536];   // 2 buf x (A 32KB | B 32KB)
  int q = blockIdx.x, n = blockIdx.y;
  int bi = bidx[n*3], by = bidx[n*3+1], bx = bidx[n*3+2];
  int t = threadIdx.x, l = t&63, wid = t>>6;
  int wm = wid>>2, wn = wid&3;
  int y0 = q*8;

  // per-thread staging invariants: task i = r4*512+t -> row=i>>3, slot=i&7
  // LDS[row][slot] <- global[row][slot ^ (row&7)]  (linear dest, pre-swizzled source)
  int offA[4], offB[4];
  #pragma unroll
  for (int r4 = 0; r4 < 4; ++r4){
    int i = r4*512 + t;
    int row = i>>3, sl_ = i&7;
    int ss = sl_ ^ (row&7);
    offA[r4] = row*COUT + ss*8;
    offB[r4] = ((row>>5)*P2 + (row&31))*COUT + ss*8;
  }
  const unsigned short* h1b = h1p + ((size_t)n*PIX2 + (size_t)y0*P2)*COUT;

  auto stage = [&](int buf, int ks){
    int tp = ks>>2, cc = ks&3;
    int dy = tp/3, dx = tp - dy*3;
    const unsigned short* wsrc = w2t + (size_t)tp*COUT*COUT + cc*64;
    const unsigned short* psrc = h1b + (size_t)(dy*P2 + dx)*COUT + cc*64;
    #pragma unroll
    for (int r4 = 0; r4 < 4; ++r4){
      GLOAD16(wsrc + offA[r4], &lds[buf*32768 + (r4*512 + t)*8]);
      GLOAD16(psrc + offB[r4], &lds[buf*32768 + 16384 + (r4*512 + t)*8]);
    }
  };

  int lr = l&15, lh = l>>4, lx7 = l&7;
  f32x4 acc[8][4] = {};

  stage(0, 0);
  __syncthreads();
  for (int ks = 0; ks < 36; ++ks){
    int cur = ks&1;
    if (ks < 35) stage(cur^1, ks+1);
    const unsigned short* Ab = &lds[cur*32768];
    const unsigned short* Bb = &lds[cur*32768 + 16384];
    bfx8 bf[4][2];
    #pragma unroll
    for (int nn = 0; nn < 4; ++nn)
      #pragma unroll
      for (int kk = 0; kk < 2; ++kk)
        bf[nn][kk] = *(const bfx8*)&Bb[(wn*64 + nn*16 + lr)*64 + ((kk*4 + lh) ^ lx7)*8];
    #pragma unroll
    for (int m = 0; m < 8; ++m){
      bfx8 a0 = *(const bfx8*)&Ab[(wm*128 + m*16 + lr)*64 + ((    lh) ^ lx7)*8];
      bfx8 a1 = *(const bfx8*)&Ab[(wm*128 + m*16 + lr)*64 + ((4 + lh) ^ lx7)*8];
      #pragma unroll
      for (int nn = 0; nn < 4; ++nn){
        acc[m][nn] = MFMA(a0, bf[nn][0], acc[m][nn]);
        acc[m][nn] = MFMA(a1, bf[nn][1], acc[m][nn]);
      }
    }
    __syncthreads();
  }

  // epilogue: raw h2 -> out active positions
  #pragma unroll
  for (int m = 0; m < 8; ++m){
    int co = wm*128 + m*16 + lh*4;
    #pragma unroll
    for (int nn = 0; nn < 4; ++nn){
      int px = wn*64 + nn*16 + lr;
      int gy = by*BSZ + y0 + (px>>5), gx = bx*BSZ + (px&31);
      #pragma unroll
      for (int j = 0; j < 4; ++j)
        out[(((size_t)bi*COUT + co + j)*HH + gy)*WW + gx] = acc[m][nn][j];
    }
  }

  // BN2 stat partials
  #pragma unroll
  for (int m = 0; m < 8; ++m){
    #pragma unroll
    for (int j = 0; j < 4; ++j){
      float s = 0.f, qq = 0.f;
      #pragma unroll
      for (int nn = 0; nn < 4; ++nn){ float v = acc[m][nn][j]; s += v; qq += v*v; }
      #pragma unroll
      for (int off = 1; off < 16; off <<= 1){
        s  += __shfl_xor(s,  off);
        qq += __shfl_xor(qq, off);
      }
      if (lr == 0){
        int co = wm*128 + m*16 + lh*4 + j;
        atomicAdd(&part[((size_t)(n&15)*COUT + co)*2],   s);
        atomicAdd(&part[((size_t)(n&15)*COUT + co)*2+1], qq);
      }
    }
  }
}

// ---------------- BN2 apply + ReLU in place on d_out active blocks ----------------
__global__ void k_bn2(float* __restrict__ out, const int* __restrict__ bidx,
                      const float* __restrict__ st){
  int cq = blockIdx.x, n = blockIdx.y, t = threadIdx.x;
  int bi = bidx[n*3], by = bidx[n*3+1], bx = bidx[n*3+2];
  int px0 = t*4; int ly = px0>>5, lx = px0&31;
  float* base = out + (size_t)bi*COUT*HH*WW + (size_t)(by*BSZ+ly)*WW + bx*BSZ + lx;
  for (int c = 0; c < 64; ++c){
    int co = cq*64 + c;
    float sc = st[co], tc = st[256+co];
    float4* p = (float4*)(base + (size_t)co*HH*WW);
    float4 v = *p;
    v.x = fmaxf(v.x*sc+tc, 0.f); v.y = fmaxf(v.y*sc+tc, 0.f);
    v.z = fmaxf(v.z*sc+tc, 0.f); v.w = fmaxf(v.w*sc+tc, 0.f);
    *p = v;
  }
}

extern "C" void kernel_launch(void* const* d_in, const int* in_sizes, int n_in,
                              void* d_out, int out_size, void* d_ws, size_t ws_size,
                              hipStream_t stream){
  const float* x   = (const float*)d_in[0];
  const float* w1  = (const float*)d_in[1];
  const float* g1  = (const float*)d_in[3];
  const float* be1 = (const float*)d_in[4];
  const float* w2  = (const float*)d_in[5];
  const float* g2  = (const float*)d_in[7];
  const float* be2 = (const float*)d_in[8];
  const float* wd  = (const float*)d_in[9];
  const float* bd  = (const float*)d_in[10];
  const int* bidx  = (const int*)d_in[11];
  float* out = (float*)d_out;
  const int nact = in_sizes[11]/3;     // 128
  const int ninact = NBLK - nact;

  char* wsp = (char*)d_ws;
  size_t off = 0;
  auto carve = [&](size_t bytes)->char*{
    char* p = wsp + off; off += (bytes + 255) & ~(size_t)255; return p;
  };
  unsigned short* h1p = (unsigned short*)carve((size_t)nact*PIX2*COUT*2 + 4096);
  unsigned short* w1b = (unsigned short*)carve((size_t)COUT*CIN*2);
  unsigned short* wdb = (unsigned short*)carve((size_t)COUT*CIN*2);
  unsigned short* w2t = (unsigned short*)carve((size_t)9*COUT*COUT*2);
  float* s1t1  = (float*)carve(512*4);
  float* s2t2  = (float*)carve(512*4);
  float* part1 = (float*)carve((size_t)16*COUT*2*4);
  float* part2 = (float*)carve((size_t)16*COUT*2*4);
  int* flags   = (int*)carve(NBLK*4);
  int* inact   = (int*)carve(NBLK*4);

  hipMemsetAsync(flags, 0, NBLK*4, stream);
  hipMemsetAsync(part1, 0, (size_t)16*COUT*2*4, stream);
  hipMemsetAsync(part2, 0, (size_t)16*COUT*2*4, stream);
  k_lists<<<1, 256, 0, stream>>>(bidx, nact, flags, inact);
  k_prep<<<2304, 256, 0, stream>>>(w1, wd, w2, w1b, wdb, w2t);
  k_gemm1<0><<<dim3(8, 2, nact), 256, 0, stream>>>(x, w1b, bidx, inact, bd, h1p, out, part1);
  k_fin<<<1, 256, 0, stream>>>(part1, g1, be1, s1t1, 1.0f/((float)nact*1024.0f));
  {
    int total = nact*PIX2;
    k_bn1<<<(total + 31)/32, 256, 0, stream>>>(h1p, s1t1, total);
  }
  k_conv2<<<dim3(4, nact), 512, 0, stream>>>(h1p, w2t, bidx, out, part2);
  k_fin<<<1, 256, 0, stream>>>(part2, g2, be2, s2t2, 1.0f/((float)nact*1024.0f));
  if (ninact > 0)
    k_gemm1<1><<<dim3(8, 2, ninact), 256, 0, stream>>>(x, wdb, bidx, inact, bd, h1p, out, part1);
  k_bn2<<<dim3(4, nact), 256, 0, stream>>>(out, bidx, s2t2);
}